// Round 2
// baseline (447.900 us; speedup 1.0000x reference)
//
#include <hip/hip_runtime.h>
#include <hip/hip_bf16.h>

typedef __hip_bfloat16 bf16;

#define THREADS 256
#define IPB 4  // images per block, weights amortized 4x

__global__ __launch_bounds__(THREADS, 2)
void lenet_fused(const float* __restrict__ x,
                 const float* __restrict__ w1, const float* __restrict__ b1,
                 const float* __restrict__ w2, const float* __restrict__ b2,
                 const float* __restrict__ wl1, const float* __restrict__ bl1,
                 const float* __restrict__ wl2, const float* __restrict__ bl2,
                 float* __restrict__ out, int batch)
{
    // LDS budget (<=64KB static): fp32 weights except wl1t/wl2 (bf16, fits cap;
    // rounding error ~1e-3 << 5.8e-2 threshold) + fp32 activation scratch.
    __shared__ float w1f[250];
    __shared__ float b1f[10];
    __shared__ float w2f[5000];
    __shared__ float b2fs[20];
    __shared__ bf16  wl1t[320 * 50];  // transposed [k][h], bf16
    __shared__ float bl1f[50];
    __shared__ bf16  wl2s[500];
    __shared__ float bl2f[10];
    __shared__ float xs[784];    // 28x28 input image
    __shared__ float p1[1440];   // pooled conv1: [10][12][12]
    __shared__ float p2[320];    // pooled conv2 flat: [20][4][4]
    __shared__ float h1[50];     // fc1 output

    const int tid = threadIdx.x;

    // ---- stage weights into LDS once per block ----
    for (int j = tid; j < 250;  j += THREADS) w1f[j]  = w1[j];
    for (int j = tid; j < 10;   j += THREADS) b1f[j]  = b1[j];
    for (int j = tid; j < 5000; j += THREADS) w2f[j]  = w2[j];
    for (int j = tid; j < 20;   j += THREADS) b2fs[j] = b2[j];
    for (int j = tid; j < 16000; j += THREADS) {
        int h = j / 320, k = j % 320;              // wl1 is [50][320]
        wl1t[k * 50 + h] = __float2bfloat16(wl1[j]);  // store transposed
    }
    for (int j = tid; j < 50;  j += THREADS) bl1f[j] = bl1[j];
    for (int j = tid; j < 500; j += THREADS) wl2s[j] = __float2bfloat16(wl2[j]);
    for (int j = tid; j < 10;  j += THREADS) bl2f[j] = bl2[j];

    const int img0 = blockIdx.x * IPB;
    for (int ii = 0; ii < IPB; ++ii) {
        const int img = img0 + ii;
        if (img >= batch) break;
        __syncthreads();  // covers weight staging (first iter) + prev-image readers

        // ---- load image ----
        const float* xim = x + (size_t)img * 784;
        for (int j = tid; j < 784; j += THREADS) xs[j] = xim[j];
        __syncthreads();

        // ---- conv1 (1->10ch, 5x5) + bias + relu + 2x2 maxpool -> p1[10][12][12]
        for (int i = tid; i < 1440; i += THREADS) {
            const int c = i / 144, p = i % 144;
            const int py = p / 12, px = p % 12;
            float acc[2][2];
            #pragma unroll
            for (int dy = 0; dy < 2; ++dy)
            #pragma unroll
            for (int dx = 0; dx < 2; ++dx) {
                const int oy = 2 * py + dy, ox = 2 * px + dx;
                float a = 0.f;
                #pragma unroll
                for (int ky = 0; ky < 5; ++ky)
                #pragma unroll
                for (int kx = 0; kx < 5; ++kx)
                    a += xs[(oy + ky) * 28 + ox + kx] * w1f[c * 25 + ky * 5 + kx];
                acc[dy][dx] = a;
            }
            float m = fmaxf(fmaxf(acc[0][0], acc[0][1]), fmaxf(acc[1][0], acc[1][1]));
            p1[i] = fmaxf(m + b1f[c], 0.f);  // relu(max(conv)+b) == relu∘pool∘(+b)
        }
        __syncthreads();

        // ---- conv2 (10->20ch, 5x5) + bias + relu + 2x2 maxpool -> p2[320]
        // lane map: act addr depends only on i%16 (16 distinct addrs/wave,
        // 4-lane same-addr broadcast), weight addr only on i/16 (4 distinct).
        for (int i = tid; i < 320; i += THREADS) {
            const int oc = i / 16, p = i % 16;
            const int py = p / 4, px = p % 4;
            float acc[2][2] = {{0.f, 0.f}, {0.f, 0.f}};
            for (int ic = 0; ic < 10; ++ic) {
                const float* w = &w2f[(oc * 10 + ic) * 25];
                const float* a = &p1[ic * 144];
                #pragma unroll
                for (int dy = 0; dy < 2; ++dy)
                #pragma unroll
                for (int dx = 0; dx < 2; ++dx) {
                    const int oy = 2 * py + dy, ox = 2 * px + dx;
                    float s = acc[dy][dx];
                    #pragma unroll
                    for (int ky = 0; ky < 5; ++ky)
                    #pragma unroll
                    for (int kx = 0; kx < 5; ++kx)
                        s += a[(oy + ky) * 12 + ox + kx] * w[ky * 5 + kx];
                    acc[dy][dx] = s;
                }
            }
            float m = fmaxf(fmaxf(acc[0][0], acc[0][1]), fmaxf(acc[1][0], acc[1][1]));
            p2[i] = fmaxf(m + b2fs[oc], 0.f);  // flat idx oc*16+py*4+px == reshape order
        }
        __syncthreads();

        // ---- fc1: 320 -> 50, relu. p2[k] broadcast; wl1t conflict-free.
        if (tid < 50) {
            float a0 = 0.f, a1 = 0.f, a2 = 0.f, a3 = 0.f;
            #pragma unroll 4
            for (int k = 0; k < 320; k += 4) {
                a0 += p2[k + 0] * __bfloat162float(wl1t[(k + 0) * 50 + tid]);
                a1 += p2[k + 1] * __bfloat162float(wl1t[(k + 1) * 50 + tid]);
                a2 += p2[k + 2] * __bfloat162float(wl1t[(k + 2) * 50 + tid]);
                a3 += p2[k + 3] * __bfloat162float(wl1t[(k + 3) * 50 + tid]);
            }
            h1[tid] = fmaxf((a0 + a1) + (a2 + a3) + bl1f[tid], 0.f);
        }
        __syncthreads();

        // ---- fc2: 50 -> 10, fp32 out
        if (tid < 10) {
            float a = bl2f[tid];
            #pragma unroll
            for (int k = 0; k < 50; ++k)
                a += h1[k] * __bfloat162float(wl2s[tid * 50 + k]);
            out[(size_t)img * 10 + tid] = a;
        }
    }
}

extern "C" void kernel_launch(void* const* d_in, const int* in_sizes, int n_in,
                              void* d_out, int out_size, void* d_ws, size_t ws_size,
                              hipStream_t stream) {
    const float* x   = (const float*)d_in[0];
    const float* w1  = (const float*)d_in[1];
    const float* b1  = (const float*)d_in[2];
    const float* w2  = (const float*)d_in[3];
    const float* b2  = (const float*)d_in[4];
    const float* wl1 = (const float*)d_in[5];
    const float* bl1 = (const float*)d_in[6];
    const float* wl2 = (const float*)d_in[7];
    const float* bl2 = (const float*)d_in[8];
    float* out = (float*)d_out;

    const int batch = in_sizes[0] / 784;  // 8192
    const int grid = (batch + IPB - 1) / IPB;
    lenet_fused<<<grid, THREADS, 0, stream>>>(x, w1, b1, w2, b2, wl1, bl1, wl2, bl2,
                                              out, batch);
}

// Round 3
// 333.991 us; speedup vs baseline: 1.3411x; 1.3411x over previous
//
#include <hip/hip_runtime.h>
#include <hip/hip_bf16.h>

typedef __hip_bfloat16 bf16;

#define T1 256
#define IPB 8   // images per block in conv kernel

__device__ __forceinline__ float bits2f(unsigned int u) {
    union { float f; unsigned int i; } x; x.i = u; return x.f;
}
__device__ __forceinline__ unsigned short f2bf(float v) {
    __hip_bfloat16 b = __float2bfloat16(v);
    return *(unsigned short*)&b;
}

// ---------------- kernel 1: conv1+pool -> conv2+pool -> p2 (global ws) --------
__global__ __launch_bounds__(T1, 4)
void conv_fused(const float* __restrict__ x,
                const float* __restrict__ w1, const float* __restrict__ b1,
                const float* __restrict__ w2, const float* __restrict__ b2,
                float* __restrict__ p2g, int batch)
{
    // LDS ~32.5KB -> 4 blocks/CU. Weights padded to stride 28 (16B-aligned rows
    // so the 25 contiguous weight reads merge into b128).
    __shared__ float w1p[10 * 28];
    __shared__ float b1f[10];
    __shared__ float w2p[200 * 28];   // [oc*10+ic][28]
    __shared__ float b2f_[20];
    __shared__ float xs[784];         // 28x28 image
    __shared__ float p1[1440];        // [10][12][12] pooled conv1

    const int tid = threadIdx.x;

    for (int j = tid; j < 250;  j += T1) w1p[(j / 25) * 28 + (j % 25)] = w1[j];
    for (int j = tid; j < 10;   j += T1) b1f[j] = b1[j];
    for (int j = tid; j < 5000; j += T1) w2p[(j / 25) * 28 + (j % 25)] = w2[j];
    for (int j = tid; j < 20;   j += T1) b2f_[j] = b2[j];

    const int img0 = blockIdx.x * IPB;
    for (int ii = 0; ii < IPB; ++ii) {
        const int img = img0 + ii;
        if (img >= batch) break;
        __syncthreads();   // weights ready (ii=0); prev image done reading p1 (ii>0)

        const float* xim = x + (size_t)img * 784;
        for (int j = tid; j < 784; j += T1) xs[j] = xim[j];
        __syncthreads();

        // conv1 (1->10ch) + bias + relu + 2x2 pool. Window cached in registers:
        // 36 LDS values + 25 weight values per 100 FMAs (vs 200 before).
        for (int i = tid; i < 1440; i += T1) {
            const int c = i / 144, p = i % 144;
            const int py = p / 12, px = p % 12;
            const float* xb = &xs[(2 * py) * 28 + 2 * px];
            float win[6][6];
            #pragma unroll
            for (int r = 0; r < 6; ++r)
                #pragma unroll
                for (int cc = 0; cc < 6; ++cc)
                    win[r][cc] = xb[r * 28 + cc];
            const float* wf = &w1p[c * 28];
            float a00 = 0.f, a01 = 0.f, a10 = 0.f, a11 = 0.f;
            #pragma unroll
            for (int ky = 0; ky < 5; ++ky)
                #pragma unroll
                for (int kx = 0; kx < 5; ++kx) {
                    const float wv = wf[ky * 5 + kx];
                    a00 += win[ky][kx]     * wv;
                    a01 += win[ky][kx + 1] * wv;
                    a10 += win[ky + 1][kx] * wv;
                    a11 += win[ky + 1][kx + 1] * wv;
                }
            const float m = fmaxf(fmaxf(a00, a01), fmaxf(a10, a11));
            p1[i] = fmaxf(m + b1f[c], 0.f);
        }
        __syncthreads();

        // conv2 (10->20ch) + bias + relu + 2x2 pool -> p2g[img][320]
        float* p2o = p2g + (size_t)img * 320;
        for (int i = tid; i < 320; i += T1) {
            const int oc = i / 16, p = i % 16;
            const int py = p / 4, px = p % 4;
            float a00 = 0.f, a01 = 0.f, a10 = 0.f, a11 = 0.f;
            for (int ic = 0; ic < 10; ++ic) {
                const float* ab = &p1[ic * 144 + (2 * py) * 12 + 2 * px];
                float win[6][6];
                #pragma unroll
                for (int r = 0; r < 6; ++r)
                    #pragma unroll
                    for (int cc = 0; cc < 6; ++cc)
                        win[r][cc] = ab[r * 12 + cc];
                const float* wf = &w2p[(oc * 10 + ic) * 28];
                #pragma unroll
                for (int ky = 0; ky < 5; ++ky)
                    #pragma unroll
                    for (int kx = 0; kx < 5; ++kx) {
                        const float wv = wf[ky * 5 + kx];
                        a00 += win[ky][kx]     * wv;
                        a01 += win[ky][kx + 1] * wv;
                        a10 += win[ky + 1][kx] * wv;
                        a11 += win[ky + 1][kx + 1] * wv;
                    }
            }
            const float m = fmaxf(fmaxf(a00, a01), fmaxf(a10, a11));
            p2o[i] = fmaxf(m + b2f_[oc], 0.f);   // flat oc*16+py*4+px == reshape order
        }
    }
}

// ---------------- kernel 2: fc1(relu) + fc2 ----------------------------------
#define IMGS2 32   // images per block

__global__ __launch_bounds__(256, 4)
void fc_fused(const float* __restrict__ p2g,
              const float* __restrict__ wl1, const float* __restrict__ bl1,
              const float* __restrict__ wl2, const float* __restrict__ bl2,
              float* __restrict__ out, int batch)
{
    __shared__ unsigned int wl1p[160 * 50];  // [k/2][h] packed bf16 pair (hi=k odd)
    __shared__ float wl2f[500];
    __shared__ float bl1f[50];
    __shared__ float bl2f[10];
    __shared__ float h1[4 * 64];             // per-wave fc1 outputs

    const int tid = threadIdx.x;

    for (int j = tid; j < 8000; j += 256) {
        const int k2 = j / 50, h = j % 50;
        const float lo = wl1[h * 320 + 2 * k2];
        const float hi = wl1[h * 320 + 2 * k2 + 1];
        wl1p[j] = (unsigned int)f2bf(lo) | ((unsigned int)f2bf(hi) << 16);
    }
    for (int j = tid; j < 500; j += 256) wl2f[j] = wl2[j];
    for (int j = tid; j < 50;  j += 256) bl1f[j] = bl1[j];
    for (int j = tid; j < 10;  j += 256) bl2f[j] = bl2[j];
    __syncthreads();

    const int w = __builtin_amdgcn_readfirstlane(tid >> 6);  // wave id 0..3
    const int h = tid & 63;
    const int hh = (h < 50) ? h : 0;

    const int base = blockIdx.x * IMGS2;
    for (int pass = 0; pass < IMGS2 / 4; ++pass) {
        const int img = base + pass * 4 + w;
        if (img < batch) {
            const float* pim = p2g + (size_t)img * 320;
            float acc = 0.f;
            #pragma unroll 4
            for (int k2 = 0; k2 < 160; ++k2) {
                const unsigned int wp = wl1p[k2 * 50 + hh];
                const float a0 = pim[2 * k2], a1 = pim[2 * k2 + 1];
                acc += a0 * bits2f(wp << 16) + a1 * bits2f(wp & 0xffff0000u);
            }
            h1[w * 64 + h] = fmaxf(acc + bl1f[hh], 0.f);
        }
        __syncthreads();
        if (tid < 40) {
            const int il = tid / 10, o = tid % 10;
            const int img2 = base + pass * 4 + il;
            if (img2 < batch) {
                float a = bl2f[o];
                #pragma unroll
                for (int k = 0; k < 50; ++k)
                    a += h1[il * 64 + k] * wl2f[o * 50 + k];
                out[(size_t)img2 * 10 + o] = a;
            }
        }
        __syncthreads();   // h1 consumed before next pass overwrites
    }
}

extern "C" void kernel_launch(void* const* d_in, const int* in_sizes, int n_in,
                              void* d_out, int out_size, void* d_ws, size_t ws_size,
                              hipStream_t stream) {
    const float* x   = (const float*)d_in[0];
    const float* w1  = (const float*)d_in[1];
    const float* b1  = (const float*)d_in[2];
    const float* w2  = (const float*)d_in[3];
    const float* b2  = (const float*)d_in[4];
    const float* wl1 = (const float*)d_in[5];
    const float* bl1 = (const float*)d_in[6];
    const float* wl2 = (const float*)d_in[7];
    const float* bl2 = (const float*)d_in[8];
    float* out = (float*)d_out;
    float* p2g = (float*)d_ws;   // batch*320 fp32 = 10.5 MB

    const int batch = in_sizes[0] / 784;  // 8192
    const int grid1 = (batch + IPB - 1) / IPB;
    conv_fused<<<grid1, T1, 0, stream>>>(x, w1, b1, w2, b2, p2g, batch);
    const int grid2 = (batch + IMGS2 - 1) / IMGS2;
    fc_fused<<<grid2, 256, 0, stream>>>(p2g, wl1, bl1, wl2, bl2, out, batch);
}

// Round 4
// 236.792 us; speedup vs baseline: 1.8915x; 1.4105x over previous
//
#include <hip/hip_runtime.h>

#define THREADS 256
#define IPB 8   // images per block; grid = batch/8 = 1024

// LDS: p1 (c*144+pq)*9+img = 12960 f, p2 8*321, h1 8*51  -> 63,744 B (2 blocks/CU)
__global__ __launch_bounds__(THREADS, 2)
void lenet_one(const float* __restrict__ x,
               const float* __restrict__ w1, const float* __restrict__ b1,
               const float* __restrict__ w2, const float* __restrict__ b2,
               const float* __restrict__ wl1, const float* __restrict__ bl1,
               const float* __restrict__ wl2, const float* __restrict__ bl2,
               float* __restrict__ out, int batch)
{
    __shared__ float p1[10 * 144 * 9];  // [c][pooled pos][img pad 9] (odd stride)
    __shared__ float p2[8 * 321];       // [img][320 pad 321]
    __shared__ float h1[8 * 51];        // [img][50 pad 51]

    const int tid = threadIdx.x;
    const int img = tid & 7;
    const int imgg = min(blockIdx.x * IPB + img, batch - 1);

    // ---------- conv1 (1->10ch) + bias + relu + pool; weights via s_load ------
    {
        const int grp = tid >> 3;                 // 0..31 position groups
        const float* xim = x + (size_t)imgg * 784;
        for (int pq = grp; pq < 144; pq += 32) {
            const int py = pq / 12, px = pq % 12;
            const float* xb = xim + (2 * py) * 28 + 2 * px;
            float win[36];                        // 6x6 input window, regs
            #pragma unroll
            for (int r = 0; r < 6; ++r)
                #pragma unroll
                for (int cc = 0; cc < 6; ++cc)
                    win[r * 6 + cc] = xb[r * 28 + cc];
            for (int c = 0; c < 10; ++c) {        // win reused across all 10 ch
                float a00 = 0.f, a01 = 0.f, a10 = 0.f, a11 = 0.f;
                #pragma unroll
                for (int ky = 0; ky < 5; ++ky)
                    #pragma unroll
                    for (int kx = 0; kx < 5; ++kx) {
                        const float wv = w1[c * 25 + ky * 5 + kx];  // uniform -> s_load
                        a00 += win[ky * 6 + kx]           * wv;
                        a01 += win[ky * 6 + kx + 1]       * wv;
                        a10 += win[(ky + 1) * 6 + kx]     * wv;
                        a11 += win[(ky + 1) * 6 + kx + 1] * wv;
                    }
                const float m = fmaxf(fmaxf(a00, a01), fmaxf(a10, a11));
                p1[(c * 144 + pq) * 9 + img] = fmaxf(m + b1[c], 0.f);
            }
        }
    }
    __syncthreads();

    // ---------- conv2 (10->20ch) + bias + relu + pool -------------------------
    {
        const int pq = (tid >> 3) & 15;           // pooled pos 4x4
        const int och = __builtin_amdgcn_readfirstlane(tid >> 7);  // 0/1, wave-uniform
        const int py = pq >> 2, px = pq & 3;
        float acc[10][4];
        #pragma unroll
        for (int o = 0; o < 10; ++o) {
            acc[o][0] = 0.f; acc[o][1] = 0.f; acc[o][2] = 0.f; acc[o][3] = 0.f;
        }
        for (int ic = 0; ic < 10; ++ic) {
            float win[36];                        // read once, reused by 10 oc
            #pragma unroll
            for (int r = 0; r < 6; ++r)
                #pragma unroll
                for (int cc = 0; cc < 6; ++cc)
                    win[r * 6 + cc] =
                        p1[(ic * 144 + (2 * py + r) * 12 + 2 * px + cc) * 9 + img];
            #pragma unroll
            for (int o = 0; o < 10; ++o) {
                const float* wp = w2 + ((och * 10 + o) * 10 + ic) * 25;  // uniform
                #pragma unroll
                for (int ky = 0; ky < 5; ++ky)
                    #pragma unroll
                    for (int kx = 0; kx < 5; ++kx) {
                        const float wv = wp[ky * 5 + kx];
                        acc[o][0] += win[ky * 6 + kx]           * wv;
                        acc[o][1] += win[ky * 6 + kx + 1]       * wv;
                        acc[o][2] += win[(ky + 1) * 6 + kx]     * wv;
                        acc[o][3] += win[(ky + 1) * 6 + kx + 1] * wv;
                    }
            }
        }
        #pragma unroll
        for (int o = 0; o < 10; ++o) {
            const float m = fmaxf(fmaxf(acc[o][0], acc[o][1]),
                                  fmaxf(acc[o][2], acc[o][3]));
            p2[img * 321 + (och * 10 + o) * 16 + pq] =
                fmaxf(m + b2[och * 10 + o], 0.f);
        }
    }
    __syncthreads();

    // ---------- fc1: 320->50 relu; lane=k, coalesced wl1, shuffle reduce ------
    {
        const int w = __builtin_amdgcn_readfirstlane(tid >> 6);  // wave 0..3
        const int lane = tid & 63;
        const int hbase = w * 13;
        const int nh = (w == 3) ? 11 : 13;       // 13+13+13+11 = 50
        for (int hi = 0; hi < nh; ++hi) {
            const int h = hbase + hi;
            float wrow[5];
            #pragma unroll
            for (int j = 0; j < 5; ++j)          // coalesced: k = lane + 64j
                wrow[j] = wl1[h * 320 + lane + 64 * j];
            for (int im = 0; im < 8; ++im) {     // weight regs reused across imgs
                float s = 0.f;
                #pragma unroll
                for (int j = 0; j < 5; ++j)
                    s += p2[im * 321 + lane + 64 * j] * wrow[j];
                #pragma unroll
                for (int off = 32; off; off >>= 1)
                    s += __shfl_xor(s, off, 64);
                if (lane == 0)
                    h1[im * 51 + h] = fmaxf(s + bl1[h], 0.f);
            }
        }
    }
    __syncthreads();

    // ---------- fc2: 50->10 -----------------------------------------------------
    if (tid < 80) {
        const int im = tid / 10, o = tid % 10;
        const int imgo = min(blockIdx.x * IPB + im, batch - 1);
        float a = bl2[o];
        #pragma unroll
        for (int h = 0; h < 50; ++h)
            a += h1[im * 51 + h] * wl2[o * 50 + h];
        out[(size_t)imgo * 10 + o] = a;          // tid 0..79 -> coalesced
    }
}

extern "C" void kernel_launch(void* const* d_in, const int* in_sizes, int n_in,
                              void* d_out, int out_size, void* d_ws, size_t ws_size,
                              hipStream_t stream) {
    const float* x   = (const float*)d_in[0];
    const float* w1  = (const float*)d_in[1];
    const float* b1  = (const float*)d_in[2];
    const float* w2  = (const float*)d_in[3];
    const float* b2  = (const float*)d_in[4];
    const float* wl1 = (const float*)d_in[5];
    const float* bl1 = (const float*)d_in[6];
    const float* wl2 = (const float*)d_in[7];
    const float* bl2 = (const float*)d_in[8];
    float* out = (float*)d_out;

    const int batch = in_sizes[0] / 784;  // 8192
    const int grid = (batch + IPB - 1) / IPB;
    lenet_one<<<grid, THREADS, 0, stream>>>(x, w1, b1, w2, b2, wl1, bl1, wl2, bl2,
                                            out, batch);
}

// Round 5
// 199.409 us; speedup vs baseline: 2.2461x; 1.1875x over previous
//
#include <hip/hip_runtime.h>

#define THREADS 256
#define IPB 8   // images per block; grid = batch/8 = 1024

// LDS: p1 fp16 (c*144+pq)*9+img = 25,920B, p2 8*321*4 = 10,272B, h1 8*51*4 = 1,632B
// total 37,824B -> 4 blocks/CU (16 waves/CU) with VGPR<=128.
__global__ __launch_bounds__(THREADS, 4)
void lenet_one(const float* __restrict__ x,
               const float* __restrict__ w1, const float* __restrict__ b1,
               const float* __restrict__ w2, const float* __restrict__ b2,
               const float* __restrict__ wl1, const float* __restrict__ bl1,
               const float* __restrict__ wl2, const float* __restrict__ bl2,
               float* __restrict__ out, int batch)
{
    __shared__ _Float16 p1[10 * 144 * 9];  // [c][pooled pos][img pad 9] fp16
    __shared__ float p2[8 * 321];          // [img][320 pad 321]
    __shared__ float h1[8 * 51];           // [img][50 pad 51]

    const int tid = threadIdx.x;
    const int img = tid & 7;
    const int imgg = min(blockIdx.x * IPB + img, batch - 1);

    // ---------- conv1 (1->10ch) + bias + relu + pool; weights via s_load ------
    {
        const int grp = tid >> 3;                 // 0..31 position groups
        const float* xim = x + (size_t)imgg * 784;
        for (int pq = grp; pq < 144; pq += 32) {
            const int py = pq / 12, px = pq % 12;
            const float* xb = xim + (2 * py) * 28 + 2 * px;
            float win[36];                        // 6x6 input window, regs
            #pragma unroll
            for (int r = 0; r < 6; ++r)
                #pragma unroll
                for (int cc = 0; cc < 6; ++cc)
                    win[r * 6 + cc] = xb[r * 28 + cc];
            for (int c = 0; c < 10; ++c) {        // win reused across all 10 ch
                float a00 = 0.f, a01 = 0.f, a10 = 0.f, a11 = 0.f;
                #pragma unroll
                for (int ky = 0; ky < 5; ++ky)
                    #pragma unroll
                    for (int kx = 0; kx < 5; ++kx) {
                        const float wv = w1[c * 25 + ky * 5 + kx];  // uniform -> s_load
                        a00 += win[ky * 6 + kx]           * wv;
                        a01 += win[ky * 6 + kx + 1]       * wv;
                        a10 += win[(ky + 1) * 6 + kx]     * wv;
                        a11 += win[(ky + 1) * 6 + kx + 1] * wv;
                    }
                const float m = fmaxf(fmaxf(a00, a01), fmaxf(a10, a11));
                p1[(c * 144 + pq) * 9 + img] = (_Float16)fmaxf(m + b1[c], 0.f);
            }
        }
    }
    __syncthreads();

    // ---------- conv2 (10->20ch) + bias + relu + pool -------------------------
    {
        const int pq = (tid >> 3) & 15;           // pooled pos 4x4
        const int och = __builtin_amdgcn_readfirstlane(tid >> 7);  // 0/1, wave-uniform
        const int py = pq >> 2, px = pq & 3;
        float acc[10][4];
        #pragma unroll
        for (int o = 0; o < 10; ++o) {
            acc[o][0] = 0.f; acc[o][1] = 0.f; acc[o][2] = 0.f; acc[o][3] = 0.f;
        }
        for (int ic = 0; ic < 10; ++ic) {
            float win[36];                        // read once, reused by 10 oc
            #pragma unroll
            for (int r = 0; r < 6; ++r)
                #pragma unroll
                for (int cc = 0; cc < 6; ++cc)
                    win[r * 6 + cc] = (float)
                        p1[(ic * 144 + (2 * py + r) * 12 + 2 * px + cc) * 9 + img];
            #pragma unroll
            for (int o = 0; o < 10; ++o) {
                const float* wp = w2 + ((och * 10 + o) * 10 + ic) * 25;  // uniform
                #pragma unroll
                for (int ky = 0; ky < 5; ++ky)
                    #pragma unroll
                    for (int kx = 0; kx < 5; ++kx) {
                        const float wv = wp[ky * 5 + kx];
                        acc[o][0] += win[ky * 6 + kx]           * wv;
                        acc[o][1] += win[ky * 6 + kx + 1]       * wv;
                        acc[o][2] += win[(ky + 1) * 6 + kx]     * wv;
                        acc[o][3] += win[(ky + 1) * 6 + kx + 1] * wv;
                    }
            }
        }
        #pragma unroll
        for (int o = 0; o < 10; ++o) {
            const float m = fmaxf(fmaxf(acc[o][0], acc[o][1]),
                                  fmaxf(acc[o][2], acc[o][3]));
            p2[img * 321 + (och * 10 + o) * 16 + pq] =
                fmaxf(m + b2[och * 10 + o], 0.f);
        }
    }
    __syncthreads();

    // ---------- fc1: 320->50 relu; lane=k, coalesced wl1, shuffle reduce ------
    {
        const int w = __builtin_amdgcn_readfirstlane(tid >> 6);  // wave 0..3
        const int lane = tid & 63;
        const int hbase = w * 13;
        const int nh = (w == 3) ? 11 : 13;       // 13+13+13+11 = 50
        for (int hi = 0; hi < nh; ++hi) {
            const int h = hbase + hi;
            float wrow[5];
            #pragma unroll
            for (int j = 0; j < 5; ++j)          // coalesced: k = lane + 64j
                wrow[j] = wl1[h * 320 + lane + 64 * j];
            for (int im = 0; im < 8; ++im) {     // weight regs reused across imgs
                float s = 0.f;
                #pragma unroll
                for (int j = 0; j < 5; ++j)
                    s += p2[im * 321 + lane + 64 * j] * wrow[j];
                #pragma unroll
                for (int off = 32; off; off >>= 1)
                    s += __shfl_xor(s, off, 64);
                if (lane == 0)
                    h1[im * 51 + h] = fmaxf(s + bl1[h], 0.f);
            }
        }
    }
    __syncthreads();

    // ---------- fc2: 50->10 -----------------------------------------------------
    if (tid < 80) {
        const int im = tid / 10, o = tid % 10;
        const int imgo = min(blockIdx.x * IPB + im, batch - 1);
        float a = bl2[o];
        #pragma unroll
        for (int h = 0; h < 50; ++h)
            a += h1[im * 51 + h] * wl2[o * 50 + h];
        out[(size_t)imgo * 10 + o] = a;          // tid 0..79 -> coalesced
    }
}

extern "C" void kernel_launch(void* const* d_in, const int* in_sizes, int n_in,
                              void* d_out, int out_size, void* d_ws, size_t ws_size,
                              hipStream_t stream) {
    const float* x   = (const float*)d_in[0];
    const float* w1  = (const float*)d_in[1];
    const float* b1  = (const float*)d_in[2];
    const float* w2  = (const float*)d_in[3];
    const float* b2  = (const float*)d_in[4];
    const float* wl1 = (const float*)d_in[5];
    const float* bl1 = (const float*)d_in[6];
    const float* wl2 = (const float*)d_in[7];
    const float* bl2 = (const float*)d_in[8];
    float* out = (float*)d_out;

    const int batch = in_sizes[0] / 784;  // 8192
    const int grid = (batch + IPB - 1) / IPB;
    lenet_one<<<grid, THREADS, 0, stream>>>(x, w1, b1, w2, b2, wl1, bl1, wl2, bl2,
                                            out, batch);
}